// Round 3
// baseline (125.966 us; speedup 1.0000x reference)
//
#include <hip/hip_runtime.h>

typedef float f32x4 __attribute__((ext_vector_type(4)));
typedef float f32x2 __attribute__((ext_vector_type(2)));
typedef __bf16 bf16x8 __attribute__((ext_vector_type(8)));

static __device__ __forceinline__ unsigned short f2bf(float v) {
    unsigned u = __builtin_bit_cast(unsigned, v);
    unsigned r = (u + 0x7FFFu + ((u >> 16) & 1u)) >> 16;
    return (unsigned short)r;
}
static __device__ __forceinline__ float bf2f(unsigned short h) {
    unsigned u = ((unsigned)h) << 16;
    return __builtin_bit_cast(float, u);
}
static __device__ __forceinline__ bf16x8 ldg8(const unsigned short* p) {
    uint4 u = *(const uint4*)p;
    return __builtin_bit_cast(bf16x8, u);
}
static __device__ __forceinline__ f32x4 mfma16(bf16x8 a, bf16x8 b, f32x4 c) {
    return __builtin_amdgcn_mfma_f32_16x16x32_bf16(a, b, c, 0, 0, 0);
}

// ---------------------------------------------------------------------------
// prep_M: simulate the 64 basis states for each f -> M_f (64x64 complex),
// bf16 hi/lo, layout [f][re/im][d][k]. (verified in R1/R2)
// ---------------------------------------------------------------------------
__global__ __launch_bounds__(256) void prep_M(const float* __restrict__ wts,
                                              unsigned short* __restrict__ Mhi,
                                              unsigned short* __restrict__ Mlo) {
    __shared__ float gls[12][8];
    const int f = blockIdx.x >> 4;
    const int tid = threadIdx.x;
    if (tid < 12) {
        int l = tid / 6, w = tid % 6;
        const float* p = wts + ((f * 2 + l) * 6 + w) * 3;
        float phi = p[0], theta = p[1], omega = p[2];
        float c, s; sincosf(0.5f * theta, &s, &c);
        float sapo, capo, samo, camo;
        sincosf(0.5f * (phi + omega), &sapo, &capo);
        sincosf(0.5f * (phi - omega), &samo, &camo);
        float* o = gls[tid];
        o[0] =  capo * c;  o[1] = -sapo * c;
        o[2] = -camo * s;  o[3] = -samo * s;
        o[4] =  camo * s;  o[5] = -samo * s;
        o[6] =  capo * c;  o[7] =  sapo * c;
    }
    __syncthreads();

    const int lane = tid & 63;
    const int wid  = tid >> 6;
    const int bas  = (blockIdx.x & 15) * 4 + wid;

    int src0 = lane, src1 = lane;
#pragma unroll
    for (int w = 5; w >= 0; --w) { int tq = (w + 1) % 6; src0 ^= ((src0 >> (5 - w)) & 1) << (5 - tq); }
#pragma unroll
    for (int w = 5; w >= 0; --w) { int tq = (w + 2) % 6; src1 ^= ((src1 >> (5 - w)) & 1) << (5 - tq); }

    float ar = (lane == bas) ? 1.0f : 0.0f, ai = 0.0f;
#pragma unroll
    for (int rep = 0; rep < 2; ++rep) {
#pragma unroll
        for (int l = 0; l < 2; ++l) {
#pragma unroll
            for (int w = 0; w < 6; ++w) {
                const float* gp = gls[l * 6 + w];
                const float4 uA = *(const float4*)gp;
                const float4 uB = *(const float4*)(gp + 4);
                const int m = 32 >> w;
                const float br = __shfl_xor(ar, m);
                const float bi = __shfl_xor(ai, m);
                const bool hi = (lane & m) != 0;
                const float cmr = hi ? uB.z : uA.x;
                const float cmi = hi ? uB.w : uA.y;
                const float cpr = hi ? uB.x : uA.z;
                const float cpi = hi ? uB.y : uA.w;
                const float nr = cmr * ar - cmi * ai + cpr * br - cpi * bi;
                const float ni = cmr * ai + cmi * ar + cpr * bi + cpi * br;
                ar = nr; ai = ni;
            }
            const int src = l ? src1 : src0;
            ar = __shfl(ar, src);
            ai = __shfl(ai, src);
        }
    }
    const int o_re = ((f * 2 + 0) * 64 + lane) * 64 + bas;
    const int o_im = ((f * 2 + 1) * 64 + lane) * 64 + bas;
    unsigned short hr = f2bf(ar);
    Mhi[o_re] = hr; Mlo[o_re] = f2bf(ar - bf2f(hr));
    unsigned short hm = f2bf(ai);
    Mhi[o_im] = hm; Mlo[o_im] = f2bf(ai - bf2f(hm));
}

// ---------------------------------------------------------------------------
// Main kernel: LDS-free. Wave owns 16 patches (cols), all 64 d (4 row-tiles).
// Lane l: patch p = l&15, k-chunks q=l>>4 and q+4 in registers.
// ---------------------------------------------------------------------------
__global__ __launch_bounds__(256) void qconv_main(
        const float* __restrict__ x,
        const unsigned short* __restrict__ Mhi,
        const unsigned short* __restrict__ Mlo,
        float* __restrict__ out) {
    const int tid  = threadIdx.x;
    const int lane = tid & 63;
    const int w    = tid >> 6;
    const int p    = lane & 15;
    const int q    = lane >> 4;

    const int n   = blockIdx.x * 64 + w * 16 + p;
    const int b   = n / 961;
    const int pos = n - b * 961;
    const int i   = pos / 31;
    const int j   = pos - i * 31;

    // chunk q -> channel q>>1, rows kh0,kh0+1 ; chunk q+4 -> channel +2
    const int cA  = q >> 1;
    const int kh0 = (q & 1) * 2;
    const float* rA0 = x + (((b * 4 + cA) * 64) + (i * 2 + kh0)) * 64 + j * 2;
    const float* rA1 = rA0 + 64;
    const float* rB0 = rA0 + 2 * 64 * 64;
    const float* rB1 = rB0 + 64;

    float vA[8], vB[8];
    *(f32x2*)&vA[0] = *(const f32x2*)rA0;
    *(f32x2*)&vA[2] = *(const f32x2*)(rA0 + 2);
    *(f32x2*)&vA[4] = *(const f32x2*)rA1;
    *(f32x2*)&vA[6] = *(const f32x2*)(rA1 + 2);
    *(f32x2*)&vB[0] = *(const f32x2*)rB0;
    *(f32x2*)&vB[2] = *(const f32x2*)(rB0 + 2);
    *(f32x2*)&vB[4] = *(const f32x2*)rB1;
    *(f32x2*)&vB[6] = *(const f32x2*)(rB1 + 2);

    float ss = 0.f;
#pragma unroll
    for (int k = 0; k < 8; ++k) ss += vA[k] * vA[k];
#pragma unroll
    for (int k = 0; k < 8; ++k) ss += vB[k] * vB[k];
    ss += __shfl_xor(ss, 16);
    ss += __shfl_xor(ss, 32);
    const float rnorm = rsqrtf(ss);

    bf16x8 bhA, blA, bhB, blB;
#pragma unroll
    for (int k = 0; k < 8; ++k) {
        float v = vA[k] * rnorm;
        __bf16 h = (__bf16)v;
        bhA[k] = h; blA[k] = (__bf16)(v - (float)h);
        float u = vB[k] * rnorm;
        __bf16 g = (__bf16)u;
        bhB[k] = g; blB[k] = (__bf16)(u - (float)g);
    }

    const int koff = q * 8;

#pragma unroll 1
    for (int f = 0; f < 4; ++f) {
        float z0 = 0.f, z1 = 0.f, z4 = 0.f, z5 = 0.f, T = 0.f;
#pragma unroll 2
        for (int t = 0; t < 4; ++t) {
            const int reb = (((f * 2 + 0) * 64) + t * 16 + p) * 64 + koff;
            const int imb = (((f * 2 + 1) * 64) + t * 16 + p) * 64 + koff;
            const bf16x8 areh0 = ldg8(Mhi + reb), areh1 = ldg8(Mhi + reb + 32);
            const bf16x8 arel0 = ldg8(Mlo + reb), arel1 = ldg8(Mlo + reb + 32);
            const bf16x8 aimh0 = ldg8(Mhi + imb), aimh1 = ldg8(Mhi + imb + 32);
            const bf16x8 aiml0 = ldg8(Mlo + imb), aiml1 = ldg8(Mlo + imb + 32);

            f32x4 cre = {0.f, 0.f, 0.f, 0.f}, cim = {0.f, 0.f, 0.f, 0.f};
            cre = mfma16(areh0, bhA, cre); cre = mfma16(areh1, bhB, cre);
            cre = mfma16(areh0, blA, cre); cre = mfma16(areh1, blB, cre);
            cre = mfma16(arel0, bhA, cre); cre = mfma16(arel1, bhB, cre);
            cim = mfma16(aimh0, bhA, cim); cim = mfma16(aimh1, bhB, cim);
            cim = mfma16(aimh0, blA, cim); cim = mfma16(aimh1, blB, cim);
            cim = mfma16(aiml0, bhA, cim); cim = mfma16(aiml1, bhB, cim);

            const float P0 = cre[0] * cre[0] + cim[0] * cim[0];
            const float P1 = cre[1] * cre[1] + cim[1] * cim[1];
            const float P2 = cre[2] * cre[2] + cim[2] * cim[2];
            const float P3 = cre[3] * cre[3] + cim[3] * cim[3];
            // d = t*16 + q*4 + r ; bits: q0,q1<-t ; q2,q3<-q ; q4,q5<-r
            const float s01 = P0 + P1, s23 = P2 + P3;
            const float d01 = P0 - P1, d23 = P2 - P3;
            const float At = s01 + s23;   // plain sum
            const float Bt = d01 + d23;   // sign by r&1   -> q5
            const float Ct = s01 - s23;   // sign by r&2   -> q4
            T  += At;
            z0 += (t & 2) ? -At : At;     // q0: d bit5 = t>>1
            z1 += (t & 1) ? -At : At;     // q1: d bit4 = t&1
            z4 += Ct;
            z5 += Bt;
        }
        float zz[6];
        zz[0] = z0;
        zz[1] = z1;
        zz[2] = (q & 2) ? -T : T;         // q2: d bit3 = q>>1
        zz[3] = (q & 1) ? -T : T;         // q3: d bit2 = q&1
        zz[4] = z4;
        zz[5] = z5;
#pragma unroll
        for (int k = 0; k < 6; ++k) {
            zz[k] += __shfl_xor(zz[k], 16);
            zz[k] += __shfl_xor(zz[k], 32);
        }
        if (lane < 16) {
            float* o = out + (b * 24 + f * 6) * 961 + pos;
#pragma unroll
            for (int k = 0; k < 6; ++k) o[k * 961] = zz[k];
        }
    }
}

extern "C" void kernel_launch(void* const* d_in, const int* in_sizes, int n_in,
                              void* d_out, int out_size, void* d_ws, size_t ws_size,
                              hipStream_t stream) {
    const float* x   = (const float*)d_in[0];   // (128, 4, 64, 64)
    const float* wts = (const float*)d_in[1];   // (4, 2, 6, 3)
    float* out = (float*)d_out;                 // (128, 24, 31, 31)

    unsigned short* Mhi = (unsigned short*)d_ws;
    unsigned short* Mlo = (unsigned short*)((char*)d_ws + 65536);

    prep_M<<<64, 256, 0, stream>>>(wts, Mhi, Mlo);

    const int npatch = 128 * 31 * 31;           // 123008 = 1922 * 64
    qconv_main<<<npatch / 64, 256, 0, stream>>>(x, Mhi, Mlo, out);
}

// Round 4
// 46.292 us; speedup vs baseline: 2.7211x; 2.7211x over previous
//
#include <hip/hip_runtime.h>

typedef float f32x2 __attribute__((ext_vector_type(2)));
typedef float f32x16 __attribute__((ext_vector_type(16)));
typedef __bf16 bf16x8 __attribute__((ext_vector_type(8)));

static __device__ __forceinline__ unsigned short f2bf(float v) {
    unsigned u = __builtin_bit_cast(unsigned, v);
    unsigned r = (u + 0x7FFFu + ((u >> 16) & 1u)) >> 16;
    return (unsigned short)r;
}
static __device__ __forceinline__ float bf2f(unsigned short h) {
    unsigned u = ((unsigned)h) << 16;
    return __builtin_bit_cast(float, u);
}
static __device__ __forceinline__ bf16x8 ldg8(const unsigned short* p) {
    uint4 u = *(const uint4*)p;
    return __builtin_bit_cast(bf16x8, u);
}
static __device__ __forceinline__ f32x16 mfma32(bf16x8 a, bf16x8 b, f32x16 c) {
    return __builtin_amdgcn_mfma_f32_32x32x16_bf16(a, b, c, 0, 0, 0);
}

// ---------------------------------------------------------------------------
// prep_M: simulate the 64 basis states for each f -> M_f (64x64 complex),
// bf16 hi/lo, layout [f][re/im][d][k]. (verified R1-R3)
// ---------------------------------------------------------------------------
__global__ __launch_bounds__(256) void prep_M(const float* __restrict__ wts,
                                              unsigned short* __restrict__ Mhi,
                                              unsigned short* __restrict__ Mlo) {
    __shared__ float gls[12][8];
    const int f = blockIdx.x >> 4;
    const int tid = threadIdx.x;
    if (tid < 12) {
        int l = tid / 6, w = tid % 6;
        const float* p = wts + ((f * 2 + l) * 6 + w) * 3;
        float phi = p[0], theta = p[1], omega = p[2];
        float c, s; sincosf(0.5f * theta, &s, &c);
        float sapo, capo, samo, camo;
        sincosf(0.5f * (phi + omega), &sapo, &capo);
        sincosf(0.5f * (phi - omega), &samo, &camo);
        float* o = gls[tid];
        o[0] =  capo * c;  o[1] = -sapo * c;
        o[2] = -camo * s;  o[3] = -samo * s;
        o[4] =  camo * s;  o[5] = -samo * s;
        o[6] =  capo * c;  o[7] =  sapo * c;
    }
    __syncthreads();

    const int lane = tid & 63;
    const int wid  = tid >> 6;
    const int bas  = (blockIdx.x & 15) * 4 + wid;

    int src0 = lane, src1 = lane;
#pragma unroll
    for (int w = 5; w >= 0; --w) { int tq = (w + 1) % 6; src0 ^= ((src0 >> (5 - w)) & 1) << (5 - tq); }
#pragma unroll
    for (int w = 5; w >= 0; --w) { int tq = (w + 2) % 6; src1 ^= ((src1 >> (5 - w)) & 1) << (5 - tq); }

    float ar = (lane == bas) ? 1.0f : 0.0f, ai = 0.0f;
#pragma unroll
    for (int rep = 0; rep < 2; ++rep) {
#pragma unroll
        for (int l = 0; l < 2; ++l) {
#pragma unroll
            for (int w = 0; w < 6; ++w) {
                const float* gp = gls[l * 6 + w];
                const float4 uA = *(const float4*)gp;
                const float4 uB = *(const float4*)(gp + 4);
                const int m = 32 >> w;
                const float br = __shfl_xor(ar, m);
                const float bi = __shfl_xor(ai, m);
                const bool hi = (lane & m) != 0;
                const float cmr = hi ? uB.z : uA.x;
                const float cmi = hi ? uB.w : uA.y;
                const float cpr = hi ? uB.x : uA.z;
                const float cpi = hi ? uB.y : uA.w;
                const float nr = cmr * ar - cmi * ai + cpr * br - cpi * bi;
                const float ni = cmr * ai + cmi * ar + cpr * bi + cpi * br;
                ar = nr; ai = ni;
            }
            const int src = l ? src1 : src0;
            ar = __shfl(ar, src);
            ai = __shfl(ai, src);
        }
    }
    const int o_re = ((f * 2 + 0) * 64 + lane) * 64 + bas;
    const int o_im = ((f * 2 + 1) * 64 + lane) * 64 + bas;
    unsigned short hr = f2bf(ar);
    Mhi[o_re] = hr; Mlo[o_re] = f2bf(ar - bf2f(hr));
    unsigned short hm = f2bf(ai);
    Mhi[o_im] = hm; Mlo[o_im] = f2bf(ai - bf2f(hm));
}

// ---------------------------------------------------------------------------
// Main: 64 patches/block, 4 waves <-> d-quarters. 32x32x16 MFMA.
// A rows = [re d16 | im d16] for wave's d-quarter; B = psi (LDS, swizzled).
// ---------------------------------------------------------------------------
__global__ __launch_bounds__(256, 2) void qconv_main(
        const float* __restrict__ x,
        const unsigned short* __restrict__ Mhi,
        const unsigned short* __restrict__ Mlo,
        float* __restrict__ out) {
    __shared__ unsigned short psiH[4096];   // [p][k] bf16, 16B-slot swizzled
    __shared__ unsigned short psiL[4096];
    __shared__ float zbuf[2 * 6 * 4 * 64];  // [fo][q][w][p]

    const int tid  = threadIdx.x;
    const int lane = tid & 63;
    const int w    = tid >> 6;
    const int n0   = blockIdx.x * 64;

    // ---- front-end: load, norm, split, stage psi ----
    {
        const int p = tid >> 2;          // patch 0..63
        const int q = tid & 3;           // channel / k-chunk
        const int n = n0 + p;
        const int b = n / 961, pos = n - b * 961;
        const int i = pos / 31, j = pos - i * 31;
        const float* base = x + (((b * 4 + q) * 64) + i * 2) * 64 + j * 2;
        float v[16];
#pragma unroll
        for (int kh = 0; kh < 4; ++kh) {
            const float* r = base + kh * 64;
            *(f32x2*)&v[kh * 4]     = *(const f32x2*)r;
            *(f32x2*)&v[kh * 4 + 2] = *(const f32x2*)(r + 2);
        }
        float ss = 0.f;
#pragma unroll
        for (int k = 0; k < 16; ++k) ss += v[k] * v[k];
        ss += __shfl_xor(ss, 1);
        ss += __shfl_xor(ss, 2);
        const float rn = rsqrtf(ss);
        unsigned hu[8], lu[8];
#pragma unroll
        for (int k2 = 0; k2 < 8; ++k2) {
            float s0 = v[2 * k2] * rn, s1 = v[2 * k2 + 1] * rn;
            __bf16 h0 = (__bf16)s0, h1 = (__bf16)s1;
            __bf16 l0 = (__bf16)(s0 - (float)h0), l1 = (__bf16)(s1 - (float)h1);
            hu[k2] = (unsigned)__builtin_bit_cast(unsigned short, h0)
                   | ((unsigned)__builtin_bit_cast(unsigned short, h1) << 16);
            lu[k2] = (unsigned)__builtin_bit_cast(unsigned short, l0)
                   | ((unsigned)__builtin_bit_cast(unsigned short, l1) << 16);
        }
        const int s0i = p * 64 + ((2 * q) ^ (p & 7)) * 8;
        const int s1i = p * 64 + ((2 * q + 1) ^ (p & 7)) * 8;
        *(uint4*)&psiH[s0i] = make_uint4(hu[0], hu[1], hu[2], hu[3]);
        *(uint4*)&psiH[s1i] = make_uint4(hu[4], hu[5], hu[6], hu[7]);
        *(uint4*)&psiL[s0i] = make_uint4(lu[0], lu[1], lu[2], lu[3]);
        *(uint4*)&psiL[s1i] = make_uint4(lu[4], lu[5], lu[6], lu[7]);
    }
    __syncthreads();

    // ---- B-fragments into registers (kept for whole kernel) ----
    bf16x8 Bh[2][4], Bl[2][4];
    {
        const int pc = lane & 31, hi = lane >> 5;
#pragma unroll
        for (int ct = 0; ct < 2; ++ct) {
            const int pp = ct * 32 + pc;
#pragma unroll
            for (int ks = 0; ks < 4; ++ks) {
                const int idx = pp * 64 + ((2 * ks + hi) ^ (pp & 7)) * 8;
                Bh[ct][ks] = __builtin_bit_cast(bf16x8, *(const uint4*)&psiH[idx]);
                Bl[ct][ks] = __builtin_bit_cast(bf16x8, *(const uint4*)&psiL[idx]);
            }
        }
    }

    // A-row base: reim from lane bit4, d = w*16 + (lane&15), k-half from lane bit5
    const int arow = ((lane >> 4) & 1) * 4096 + (w * 16 + (lane & 15)) * 64 + (lane >> 5) * 8;
    const int hi5 = lane >> 5;

#pragma unroll 1
    for (int fp = 0; fp < 2; ++fp) {
#pragma unroll 1
        for (int fo = 0; fo < 2; ++fo) {
            const int f = fp * 2 + fo;
            f32x16 C0, C1;
#pragma unroll
            for (int r = 0; r < 16; ++r) { C0[r] = 0.f; C1[r] = 0.f; }
#pragma unroll
            for (int ks = 0; ks < 4; ++ks) {
                const int off = f * 8192 + arow + ks * 16;
                const bf16x8 Ah = ldg8(Mhi + off);
                const bf16x8 Al = ldg8(Mlo + off);
                C0 = mfma32(Ah, Bh[0][ks], C0);
                C1 = mfma32(Ah, Bh[1][ks], C1);
                C0 = mfma32(Ah, Bl[0][ks], C0);
                C1 = mfma32(Ah, Bl[1][ks], C1);
                C0 = mfma32(Al, Bh[0][ks], C0);
                C1 = mfma32(Al, Bh[1][ks], C1);
            }
            // epilogue: P lane-local (re=regs 0-7, im=regs 8-15, same d)
#pragma unroll
            for (int ct = 0; ct < 2; ++ct) {
                const f32x16 Cv = ct ? C1 : C0;
                float P[8];
#pragma unroll
                for (int r = 0; r < 8; ++r) P[r] = Cv[r] * Cv[r] + Cv[r + 8] * Cv[r + 8];
                const float e0 = P[0] + P[1], o0 = P[0] - P[1];
                const float e1 = P[2] + P[3], o1 = P[2] - P[3];
                const float e2 = P[4] + P[5], o2 = P[4] - P[5];
                const float e3 = P[6] + P[7], o3 = P[6] - P[7];
                const float s01 = e0 + e1, s23 = e2 + e3;
                float S  = s01 + s23;
                float Z2 = s01 - s23;                 // sign by d&8  (r>>2)
                float Z4 = (e0 - e1) + (e2 - e3);     // sign by d&2  (r&2)
                float Z5 = o0 + o1 + o2 + o3;         // sign by d&1  (r&1)
                float Z3 = hi5 ? -S : S;              // sign by d&4  (hi)
                S  += __shfl_xor(S, 32);
                Z2 += __shfl_xor(Z2, 32);
                Z3 += __shfl_xor(Z3, 32);
                Z4 += __shfl_xor(Z4, 32);
                Z5 += __shfl_xor(Z5, 32);
                if (lane < 32) {
                    const int pp = ct * 32 + lane;
                    zbuf[((fo * 6 + 0) * 4 + w) * 64 + pp] = (w & 2) ? -S : S;
                    zbuf[((fo * 6 + 1) * 4 + w) * 64 + pp] = (w & 1) ? -S : S;
                    zbuf[((fo * 6 + 2) * 4 + w) * 64 + pp] = Z2;
                    zbuf[((fo * 6 + 3) * 4 + w) * 64 + pp] = Z3;
                    zbuf[((fo * 6 + 4) * 4 + w) * 64 + pp] = Z4;
                    zbuf[((fo * 6 + 5) * 4 + w) * 64 + pp] = Z5;
                }
            }
        }
        __syncthreads();
        // ---- combine across waves + store (2 f's worth) ----
#pragma unroll 1
        for (int u = tid; u < 768; u += 256) {
            const int fo  = u / 384;
            const int rem = u - fo * 384;
            const int q   = rem >> 6;
            const int p   = rem & 63;
            const int zb  = (fo * 6 + q) * 4 * 64 + p;
            const float sum = zbuf[zb] + zbuf[zb + 64] + zbuf[zb + 128] + zbuf[zb + 192];
            const int f = fp * 2 + fo;
            const int n = n0 + p;
            const int b = n / 961, pos = n - b * 961;
            out[(b * 24 + f * 6 + q) * 961 + pos] = sum;
        }
        __syncthreads();
    }
}

extern "C" void kernel_launch(void* const* d_in, const int* in_sizes, int n_in,
                              void* d_out, int out_size, void* d_ws, size_t ws_size,
                              hipStream_t stream) {
    const float* x   = (const float*)d_in[0];   // (128, 4, 64, 64)
    const float* wts = (const float*)d_in[1];   // (4, 2, 6, 3)
    float* out = (float*)d_out;                 // (128, 24, 31, 31)

    unsigned short* Mhi = (unsigned short*)d_ws;
    unsigned short* Mlo = (unsigned short*)((char*)d_ws + 65536);

    prep_M<<<64, 256, 0, stream>>>(wts, Mhi, Mlo);

    const int npatch = 128 * 31 * 31;           // 123008 = 1922 * 64
    qconv_main<<<npatch / 64, 256, 0, stream>>>(x, Mhi, Mlo, out);
}

// Round 5
// 45.766 us; speedup vs baseline: 2.7524x; 1.0115x over previous
//
#include <hip/hip_runtime.h>

typedef float f32x2 __attribute__((ext_vector_type(2)));
typedef float f32x16 __attribute__((ext_vector_type(16)));
typedef __bf16 bf16x8 __attribute__((ext_vector_type(8)));

static __device__ __forceinline__ unsigned short f2bf(float v) {
    unsigned u = __builtin_bit_cast(unsigned, v);
    unsigned r = (u + 0x7FFFu + ((u >> 16) & 1u)) >> 16;
    return (unsigned short)r;
}
static __device__ __forceinline__ float bf2f(unsigned short h) {
    unsigned u = ((unsigned)h) << 16;
    return __builtin_bit_cast(float, u);
}
static __device__ __forceinline__ bf16x8 ldg8(const unsigned short* p) {
    uint4 u = *(const uint4*)p;
    return __builtin_bit_cast(bf16x8, u);
}
static __device__ __forceinline__ f32x16 mfma32(bf16x8 a, bf16x8 b, f32x16 c) {
    return __builtin_amdgcn_mfma_f32_32x32x16_bf16(a, b, c, 0, 0, 0);
}

// ---------------------------------------------------------------------------
// prep_M: simulate the 64 basis states for each f -> M_f (64x64 complex),
// bf16 hi/lo, layout [f][re/im][d][k]. (verified R1-R4)
// ---------------------------------------------------------------------------
__global__ __launch_bounds__(256) void prep_M(const float* __restrict__ wts,
                                              unsigned short* __restrict__ Mhi,
                                              unsigned short* __restrict__ Mlo) {
    __shared__ float gls[12][8];
    const int f = blockIdx.x >> 4;
    const int tid = threadIdx.x;
    if (tid < 12) {
        int l = tid / 6, w = tid % 6;
        const float* p = wts + ((f * 2 + l) * 6 + w) * 3;
        float phi = p[0], theta = p[1], omega = p[2];
        float c, s; sincosf(0.5f * theta, &s, &c);
        float sapo, capo, samo, camo;
        sincosf(0.5f * (phi + omega), &sapo, &capo);
        sincosf(0.5f * (phi - omega), &samo, &camo);
        float* o = gls[tid];
        o[0] =  capo * c;  o[1] = -sapo * c;
        o[2] = -camo * s;  o[3] = -samo * s;
        o[4] =  camo * s;  o[5] = -samo * s;
        o[6] =  capo * c;  o[7] =  sapo * c;
    }
    __syncthreads();

    const int lane = tid & 63;
    const int wid  = tid >> 6;
    const int bas  = (blockIdx.x & 15) * 4 + wid;

    int src0 = lane, src1 = lane;
#pragma unroll
    for (int w = 5; w >= 0; --w) { int tq = (w + 1) % 6; src0 ^= ((src0 >> (5 - w)) & 1) << (5 - tq); }
#pragma unroll
    for (int w = 5; w >= 0; --w) { int tq = (w + 2) % 6; src1 ^= ((src1 >> (5 - w)) & 1) << (5 - tq); }

    float ar = (lane == bas) ? 1.0f : 0.0f, ai = 0.0f;
#pragma unroll
    for (int rep = 0; rep < 2; ++rep) {
#pragma unroll
        for (int l = 0; l < 2; ++l) {
#pragma unroll
            for (int w = 0; w < 6; ++w) {
                const float* gp = gls[l * 6 + w];
                const float4 uA = *(const float4*)gp;
                const float4 uB = *(const float4*)(gp + 4);
                const int m = 32 >> w;
                const float br = __shfl_xor(ar, m);
                const float bi = __shfl_xor(ai, m);
                const bool hi = (lane & m) != 0;
                const float cmr = hi ? uB.z : uA.x;
                const float cmi = hi ? uB.w : uA.y;
                const float cpr = hi ? uB.x : uA.z;
                const float cpi = hi ? uB.y : uA.w;
                const float nr = cmr * ar - cmi * ai + cpr * br - cpi * bi;
                const float ni = cmr * ai + cmi * ar + cpr * bi + cpi * br;
                ar = nr; ai = ni;
            }
            const int src = l ? src1 : src0;
            ar = __shfl(ar, src);
            ai = __shfl(ai, src);
        }
    }
    const int o_re = ((f * 2 + 0) * 64 + lane) * 64 + bas;
    const int o_im = ((f * 2 + 1) * 64 + lane) * 64 + bas;
    unsigned short hr = f2bf(ar);
    Mhi[o_re] = hr; Mlo[o_re] = f2bf(ar - bf2f(hr));
    unsigned short hm = f2bf(ai);
    Mhi[o_im] = hm; Mlo[o_im] = f2bf(ai - bf2f(hm));
}

// ---------------------------------------------------------------------------
// Main: 64 patches/block, 4 waves <-> d-quarters. 32x32x16 MFMA.
// LDS: 16 KB union — psi staging (dead after B-frag load) reused as zbuf.
// ---------------------------------------------------------------------------
__global__ __launch_bounds__(256, 4) void qconv_main(
        const float* __restrict__ x,
        const unsigned short* __restrict__ Mhi,
        const unsigned short* __restrict__ Mlo,
        float* __restrict__ out) {
    __shared__ __align__(16) unsigned char smem[16384];
    unsigned short* psiH = (unsigned short*)smem;            // 8 KB
    unsigned short* psiL = (unsigned short*)(smem + 8192);   // 8 KB
    float* zbuf = (float*)smem;                              // 12 KB, reused

    const int tid  = threadIdx.x;
    const int lane = tid & 63;
    const int w    = tid >> 6;
    const int n0   = blockIdx.x * 64;

    // ---- front-end: load, norm, split, stage psi ----
    {
        const int p = tid >> 2;          // patch 0..63
        const int q = tid & 3;           // channel / k-chunk
        const int n = n0 + p;
        const int b = n / 961, pos = n - b * 961;
        const int i = pos / 31, j = pos - i * 31;
        const float* base = x + (((b * 4 + q) * 64) + i * 2) * 64 + j * 2;
        float v[16];
#pragma unroll
        for (int kh = 0; kh < 4; ++kh) {
            const float* r = base + kh * 64;
            *(f32x2*)&v[kh * 4]     = *(const f32x2*)r;
            *(f32x2*)&v[kh * 4 + 2] = *(const f32x2*)(r + 2);
        }
        float ss = 0.f;
#pragma unroll
        for (int k = 0; k < 16; ++k) ss += v[k] * v[k];
        ss += __shfl_xor(ss, 1);
        ss += __shfl_xor(ss, 2);
        const float rn = rsqrtf(ss);
        unsigned hu[8], lu[8];
#pragma unroll
        for (int k2 = 0; k2 < 8; ++k2) {
            float s0 = v[2 * k2] * rn, s1 = v[2 * k2 + 1] * rn;
            __bf16 h0 = (__bf16)s0, h1 = (__bf16)s1;
            __bf16 l0 = (__bf16)(s0 - (float)h0), l1 = (__bf16)(s1 - (float)h1);
            hu[k2] = (unsigned)__builtin_bit_cast(unsigned short, h0)
                   | ((unsigned)__builtin_bit_cast(unsigned short, h1) << 16);
            lu[k2] = (unsigned)__builtin_bit_cast(unsigned short, l0)
                   | ((unsigned)__builtin_bit_cast(unsigned short, l1) << 16);
        }
        const int s0i = p * 64 + ((2 * q) ^ (p & 7)) * 8;
        const int s1i = p * 64 + ((2 * q + 1) ^ (p & 7)) * 8;
        *(uint4*)&psiH[s0i] = make_uint4(hu[0], hu[1], hu[2], hu[3]);
        *(uint4*)&psiH[s1i] = make_uint4(hu[4], hu[5], hu[6], hu[7]);
        *(uint4*)&psiL[s0i] = make_uint4(lu[0], lu[1], lu[2], lu[3]);
        *(uint4*)&psiL[s1i] = make_uint4(lu[4], lu[5], lu[6], lu[7]);
    }
    __syncthreads();

    // ---- B-fragments into registers (kept for whole kernel) ----
    bf16x8 Bh[2][4], Bl[2][4];
    {
        const int pc = lane & 31, hi = lane >> 5;
#pragma unroll
        for (int ct = 0; ct < 2; ++ct) {
            const int pp = ct * 32 + pc;
#pragma unroll
            for (int ks = 0; ks < 4; ++ks) {
                const int idx = pp * 64 + ((2 * ks + hi) ^ (pp & 7)) * 8;
                Bh[ct][ks] = __builtin_bit_cast(bf16x8, *(const uint4*)&psiH[idx]);
                Bl[ct][ks] = __builtin_bit_cast(bf16x8, *(const uint4*)&psiL[idx]);
            }
        }
    }
    __syncthreads();   // psi LDS is now dead; safe to reuse as zbuf

    // A-row base: reim from lane bit4, d = w*16 + (lane&15), k-half from lane bit5
    const int arow = ((lane >> 4) & 1) * 4096 + (w * 16 + (lane & 15)) * 64 + (lane >> 5) * 8;
    const int hi5 = lane >> 5;

#pragma unroll 1
    for (int fp = 0; fp < 2; ++fp) {
#pragma unroll 1
        for (int fo = 0; fo < 2; ++fo) {
            const int f = fp * 2 + fo;
            f32x16 C0, C1;
#pragma unroll
            for (int r = 0; r < 16; ++r) { C0[r] = 0.f; C1[r] = 0.f; }
#pragma unroll
            for (int ks = 0; ks < 4; ++ks) {
                const int off = f * 8192 + arow + ks * 16;
                const bf16x8 Ah = ldg8(Mhi + off);
                const bf16x8 Al = ldg8(Mlo + off);
                C0 = mfma32(Ah, Bh[0][ks], C0);
                C1 = mfma32(Ah, Bh[1][ks], C1);
                C0 = mfma32(Ah, Bl[0][ks], C0);
                C1 = mfma32(Ah, Bl[1][ks], C1);
                C0 = mfma32(Al, Bh[0][ks], C0);
                C1 = mfma32(Al, Bh[1][ks], C1);
            }
            // epilogue: P lane-local (re=regs 0-7, im=regs 8-15, same d)
#pragma unroll
            for (int ct = 0; ct < 2; ++ct) {
                const f32x16 Cv = ct ? C1 : C0;
                float P[8];
#pragma unroll
                for (int r = 0; r < 8; ++r) P[r] = Cv[r] * Cv[r] + Cv[r + 8] * Cv[r + 8];
                const float e0 = P[0] + P[1], o0 = P[0] - P[1];
                const float e1 = P[2] + P[3], o1 = P[2] - P[3];
                const float e2 = P[4] + P[5], o2 = P[4] - P[5];
                const float e3 = P[6] + P[7], o3 = P[6] - P[7];
                const float s01 = e0 + e1, s23 = e2 + e3;
                float S  = s01 + s23;
                float Z2 = s01 - s23;                 // sign by d&8  (r>>2)
                float Z4 = (e0 - e1) + (e2 - e3);     // sign by d&2  (r&2)
                float Z5 = o0 + o1 + o2 + o3;         // sign by d&1  (r&1)
                float Z3 = hi5 ? -S : S;              // sign by d&4  (hi)
                S  += __shfl_xor(S, 32);
                Z2 += __shfl_xor(Z2, 32);
                Z3 += __shfl_xor(Z3, 32);
                Z4 += __shfl_xor(Z4, 32);
                Z5 += __shfl_xor(Z5, 32);
                if (lane < 32) {
                    const int pp = ct * 32 + lane;
                    zbuf[((fo * 6 + 0) * 4 + w) * 64 + pp] = (w & 2) ? -S : S;
                    zbuf[((fo * 6 + 1) * 4 + w) * 64 + pp] = (w & 1) ? -S : S;
                    zbuf[((fo * 6 + 2) * 4 + w) * 64 + pp] = Z2;
                    zbuf[((fo * 6 + 3) * 4 + w) * 64 + pp] = Z3;
                    zbuf[((fo * 6 + 4) * 4 + w) * 64 + pp] = Z4;
                    zbuf[((fo * 6 + 5) * 4 + w) * 64 + pp] = Z5;
                }
            }
        }
        __syncthreads();
        // ---- combine across waves + store (2 f's worth) ----
#pragma unroll 1
        for (int u = tid; u < 768; u += 256) {
            const int fo  = u / 384;
            const int rem = u - fo * 384;
            const int q   = rem >> 6;
            const int p   = rem & 63;
            const int zb  = (fo * 6 + q) * 4 * 64 + p;
            const float sum = zbuf[zb] + zbuf[zb + 64] + zbuf[zb + 128] + zbuf[zb + 192];
            const int f = fp * 2 + fo;
            const int n = n0 + p;
            const int b = n / 961, pos = n - b * 961;
            out[(b * 24 + f * 6 + q) * 961 + pos] = sum;
        }
        __syncthreads();
    }
}

extern "C" void kernel_launch(void* const* d_in, const int* in_sizes, int n_in,
                              void* d_out, int out_size, void* d_ws, size_t ws_size,
                              hipStream_t stream) {
    const float* x   = (const float*)d_in[0];   // (128, 4, 64, 64)
    const float* wts = (const float*)d_in[1];   // (4, 2, 6, 3)
    float* out = (float*)d_out;                 // (128, 24, 31, 31)

    unsigned short* Mhi = (unsigned short*)d_ws;
    unsigned short* Mlo = (unsigned short*)((char*)d_ws + 65536);

    prep_M<<<64, 256, 0, stream>>>(wts, Mhi, Mlo);

    const int npatch = 128 * 31 * 31;           // 123008 = 1922 * 64
    qconv_main<<<npatch / 64, 256, 0, stream>>>(x, Mhi, Mlo, out);
}